// Round 21
// baseline (225.781 us; speedup 1.0000x reference)
//
#include <hip/hip_runtime.h>
#include <hip/hip_bf16.h>
#include <cstdint>

typedef __hip_bfloat16 bf16;
typedef __attribute__((ext_vector_type(8))) short bf16x8;
typedef __attribute__((ext_vector_type(4))) float f32x4;
typedef __attribute__((ext_vector_type(4))) int i32x4;

#define T_SEQ 2048
#define DMODEL 1024
#define NHEAD 16
#define DHEAD 64
#define MROWS 4096

typedef const __attribute__((address_space(1))) void* gas_ptr;
typedef __attribute__((address_space(3))) void* las_ptr;

static __device__ __forceinline__ f32x4 mfma16(bf16x8 a, bf16x8 b, f32x4 c) {
  return __builtin_amdgcn_mfma_f32_16x16x32_bf16(a, b, c, 0, 0, 0);
}
static __device__ __forceinline__ void gload_lds16(const void* g, void* l) {
  __builtin_amdgcn_global_load_lds((gas_ptr)g, (las_ptr)l, 16, 0, 0);
}
static __device__ __forceinline__ float b2f(unsigned short u) {
  union { unsigned int i; float f; } x; x.i = ((unsigned int)u) << 16; return x.f;
}
static __device__ __forceinline__ unsigned short f2bu(float f) {
  __hip_bfloat16 h = __float2bfloat16(f);
  unsigned short u; __builtin_memcpy(&u, &h, 2); return u;
}
// truncation pack: low16 = bf16_trunc(a), high16 = bf16_trunc(b); a,b >= 0
static __device__ __forceinline__ int tpack(float a, float b) {
  const unsigned ua = __builtin_bit_cast(unsigned, a);
  const unsigned ub = __builtin_bit_cast(unsigned, b);
  return (int)((ua >> 16) | (ub & 0xFFFF0000u));
}

// ------- prep: weights fp32->bf16 (blocks 0..10239) + rms1 (blocks 10240+) ---
// gate/up rows are INTERLEAVED into WGU: row 2i = gate_i, row 2i+1 = up_i.
__global__ __launch_bounds__(256) void prep_k(const float* __restrict__ a,
                                              const float* __restrict__ b,
                                              const float* __restrict__ c,
                                              const float* __restrict__ d,
                                              const float* __restrict__ e,
                                              bf16* __restrict__ out,
                                              const float* __restrict__ x,
                                              const float* __restrict__ ln1w,
                                              bf16* __restrict__ H) {
  if (blockIdx.x < 10240) {
    const int idx = (blockIdx.x * 256 + threadIdx.x) * 4;
    const float* src;
    int off, dst;
    if (idx < 3145728) {                     // qkv
      src = a; off = idx; dst = idx;
    } else if (idx < 4194304) {              // o
      src = b; off = idx - 3145728; dst = idx;
    } else if (idx < 6291456) {              // gate -> WGU even rows
      src = c; off = idx - 4194304;
      dst = 4194304 + ((off >> 10) << 11) + (off & 1023);
    } else if (idx < 8388608) {              // up -> WGU odd rows
      src = d; off = idx - 6291456;
      dst = 4194304 + ((off >> 10) << 11) + 1024 + (off & 1023);
    } else {                                 // down
      src = e; off = idx - 8388608; dst = idx;
    }
    const float4 v = *(const float4*)(src + off);
    ushort4 ov;
    ov.x = f2bu(v.x); ov.y = f2bu(v.y); ov.z = f2bu(v.z); ov.w = f2bu(v.w);
    *(ushort4*)((unsigned short*)out + dst) = ov;
  } else {
    const int row = blockIdx.x - 10240;
    const int tid = threadIdx.x;
    const float4 v = ((const float4*)(x + (size_t)row * DMODEL))[tid];
    float ss = v.x * v.x + v.y * v.y + v.z * v.z + v.w * v.w;
#pragma unroll
    for (int off = 32; off; off >>= 1) ss += __shfl_xor(ss, off);
    __shared__ float red[4];
    if ((tid & 63) == 0) red[tid >> 6] = ss;
    __syncthreads();
    const float tot = red[0] + red[1] + red[2] + red[3];
    const float rinv = rsqrtf(tot * (1.f / DMODEL) + 1e-6f);
    const float4 wv = ((const float4*)ln1w)[tid];
    bf16* o = H + (size_t)row * DMODEL + tid * 4;
    o[0] = __float2bfloat16(v.x * rinv * wv.x);
    o[1] = __float2bfloat16(v.y * rinv * wv.y);
    o[2] = __float2bfloat16(v.z * rinv * wv.z);
    o[3] = __float2bfloat16(v.w * rinv * wv.w);
  }
}

// ---------------- RMSNorm: fp32 in -> bf16 out (used for rms2) ----------------
__global__ __launch_bounds__(256) void rms_k(const float* __restrict__ x,
                                             const float* __restrict__ w,
                                             bf16* __restrict__ out) {
  const int row = blockIdx.x;
  const int tid = threadIdx.x;
  const float4 v = ((const float4*)(x + (size_t)row * DMODEL))[tid];
  float ss = v.x * v.x + v.y * v.y + v.z * v.z + v.w * v.w;
#pragma unroll
  for (int off = 32; off; off >>= 1) ss += __shfl_xor(ss, off);
  __shared__ float red[4];
  if ((tid & 63) == 0) red[tid >> 6] = ss;
  __syncthreads();
  const float tot = red[0] + red[1] + red[2] + red[3];
  const float rinv = rsqrtf(tot * (1.f / DMODEL) + 1e-6f);
  const float4 wv = ((const float4*)w)[tid];
  bf16* o = out + (size_t)row * DMODEL + tid * 4;
  o[0] = __float2bfloat16(v.x * rinv * wv.x);
  o[1] = __float2bfloat16(v.y * rinv * wv.y);
  o[2] = __float2bfloat16(v.z * rinv * wv.z);
  o[3] = __float2bfloat16(v.w * rinv * wv.w);
}

// ---------------- GEMM: C = A(M,K) x Bw(N,K)^T, bf16 in, fp32 accum ----------------
// r14/r15-verified: 2-barrier structure, BK=64, both-sides 16B-slot XOR swizzle
// (bank conflicts = 0 measured). V^T stores PACKED (8B).
// EPI: 1 = qkv scatter: Q,K as (B,H,T,64) to o0/o1; V TRANSPOSED (B,H,64,T) to o2
//      2 = fp32 store o0 = res + C (ld=N)
//      4 = fused gate/up (B = row-interleaved WGU): even col=gate, odd col=up;
//          even lanes compute silu(g)*u -> bf16 store to o0 (ld = N/2)
template <int K, int EPI>
__global__ __launch_bounds__(256) void gemm_bt(const bf16* __restrict__ A,
                                               const bf16* __restrict__ Bw, int N,
                                               void* __restrict__ o0, void* __restrict__ o1,
                                               void* __restrict__ o2,
                                               const float* __restrict__ res) {
  __shared__ bf16 As[128 * 64];
  __shared__ bf16 Bs[128 * 64];
  const int bn0 = blockIdx.x * 128;
  const int bm0 = blockIdx.y * 128;
  const int tid = threadIdx.x;
  const int wave = tid >> 6, lane = tid & 63;
  const int wr = wave >> 1, wc = wave & 1;
  const int fr = lane & 15, u = lane >> 4, r4 = u * 4;
  const int srow = lane >> 3;              // 0..7 within 8-row chunk
  const int sslot = (lane & 7) ^ srow;     // pre-swizzled source 16B slot
  const int fsw = fr & 7;

  const f32x4 fzero = {0.f, 0.f, 0.f, 0.f};
  f32x4 acc[4][4];
#pragma unroll
  for (int i = 0; i < 4; i++)
#pragma unroll
    for (int j = 0; j < 4; j++) acc[i][j] = fzero;

  const bf16* gA = A + (size_t)(bm0 + wave * 32 + srow) * K + sslot * 8;
  const bf16* gB = Bw + (size_t)(bn0 + wave * 32 + srow) * K + sslot * 8;

  for (int k0 = 0; k0 < K; k0 += 64) {
#pragma unroll
    for (int j = 0; j < 4; j++)
      gload_lds16(gA + (size_t)(j * 8) * K + k0, &As[(wave * 32 + j * 8) * 64]);
#pragma unroll
    for (int j = 0; j < 4; j++)
      gload_lds16(gB + (size_t)(j * 8) * K + k0, &Bs[(wave * 32 + j * 8) * 64]);
    __syncthreads();
#pragma unroll
    for (int kh = 0; kh < 2; kh++) {
      const int slot8 = ((kh * 4 + u) ^ fsw) * 8;
      bf16x8 af[4], bfr[4];
#pragma unroll
      for (int mr = 0; mr < 4; mr++)
        af[mr] = *(const bf16x8*)&As[(wr * 64 + mr * 16 + fr) * 64 + slot8];
#pragma unroll
      for (int nr = 0; nr < 4; nr++)
        bfr[nr] = *(const bf16x8*)&Bs[(wc * 64 + nr * 16 + fr) * 64 + slot8];
#pragma unroll
      for (int mr = 0; mr < 4; mr++)
#pragma unroll
        for (int nr = 0; nr < 4; nr++)
          acc[mr][nr] = mfma16(af[mr], bfr[nr], acc[mr][nr]);
    }
    __syncthreads();
  }

#pragma unroll
  for (int mr = 0; mr < 4; mr++) {
#pragma unroll
    for (int nr = 0; nr < 4; nr++) {
      if (EPI == 1) {
        const int col = bn0 + wc * 64 + nr * 16 + fr;
        const int sel = col >> 10;
        const int n = col & 1023;
        const int h = n >> 6, d = n & 63;
        const int row0 = bm0 + wr * 64 + mr * 16 + r4;  // 4 consecutive rows
        const int b = row0 >> 11, t0 = row0 & 2047;     // never crosses 2048
        if (sel == 2) {
          // V transposed (B,H,64,T): 4 consecutive t -> one 8B store
          ushort4 ov;
          ov.x = f2bu(acc[mr][nr][0]);
          ov.y = f2bu(acc[mr][nr][1]);
          ov.z = f2bu(acc[mr][nr][2]);
          ov.w = f2bu(acc[mr][nr][3]);
          *(ushort4*)((unsigned short*)o2 +
                      (((size_t)(b * NHEAD + h)) * DHEAD + d) * T_SEQ + t0) = ov;
        } else {
          bf16* dst = (sel == 0) ? (bf16*)o0 : (bf16*)o1;
#pragma unroll
          for (int r = 0; r < 4; r++)
            dst[(((size_t)(b * NHEAD + h)) * T_SEQ + t0 + r) * DHEAD + d] =
                __float2bfloat16(acc[mr][nr][r]);
        }
      } else {
#pragma unroll
        for (int r = 0; r < 4; r++) {
          const int row = bm0 + wr * 64 + mr * 16 + r4 + r;
          const int col = bn0 + wc * 64 + nr * 16 + fr;
          const float vsum = acc[mr][nr][r];
          if (EPI == 2) {
            ((float*)o0)[(size_t)row * N + col] = res[(size_t)row * N + col] + vsum;
          } else {  // EPI == 4: fused gate/up + silu
            const float other = __shfl_xor(vsum, 1);
            if ((fr & 1) == 0) {
              const float g = vsum, uu = other;
              const float s = g / (1.f + __expf(-g));
              ((bf16*)o0)[(size_t)row * (N >> 1) + (col >> 1)] =
                  __float2bfloat16(s * uu);
            }
          }
        }
      }
    }
  }
}

// ---------------- causal flash attention: split extended to qt>=8 ------------
// r17/r20-verified compute body byte-identical. Task decomposition changed to
// flatten block durations (the 26% occupancy tail was light qt=8..15 blocks
// running up to 32 steps): split blocks cover qt 8..31 (nb<=16), light only
// qt 0..7 (nb<=16) -> ALL 1792 blocks uniform <=16 steps.
// Partials: qt>=16 rows 1024..2047 -> pO (stride 1024); qt 8..15 rows
// 512..1023 -> pO+4194304 (stride 512). pL likewise (+65536).
__global__ __launch_bounds__(256) void attn_k(const bf16* __restrict__ qb,
                                              const bf16* __restrict__ kb,
                                              const bf16* __restrict__ vt,
                                              bf16* __restrict__ y,
                                              unsigned short* __restrict__ pO,
                                              float* __restrict__ pL) {
  const int wave = threadIdx.x >> 6, lane = threadIdx.x & 63;
  const int bid = blockIdx.x;
  int bh, qt, ks0, nb, heavy, hs;
  if (bid < 1536) {
    const int c = bid & 7, r = bid >> 3;
    bh = c * 4 + (r & 3);
    const int idx = r >> 2;          // 0..47
    qt = 31 - (idx >> 1);            // 31..8
    hs = idx & 1;
    heavy = 1;
    nb = qt + 1;                     // half of the 2qt+2 32-key tiles
    ks0 = hs * nb;
  } else {
    const int bd = bid - 1536;
    const int c = bd & 7, r = bd >> 3;
    bh = c * 4 + (r & 3);
    qt = 7 - (r >> 2);               // 7..0, longest light first
    hs = 0;
    heavy = 0;
    nb = 2 * qt + 2;
    ks0 = 0;
  }
  const int b = bh >> 4, h = bh & 15;
  const int fr = lane & 15, g8 = (lane >> 4) * 8, r4 = (lane >> 4) * 4;
  const int u = lane >> 4;
  const int src1 = fr + ((u & 1) << 5);
  const int src2 = src1 + 16;
  const bool hB = u >= 2;

  const bf16* qp = qb + (size_t)bh * T_SEQ * DHEAD;
  const bf16* kp = kb + (size_t)bh * T_SEQ * DHEAD;
  const bf16* vp = vt + (size_t)bh * DHEAD * T_SEQ;

  __shared__ char Ks[2][4096];  // 32 rows x 128B, slot-swizzled
  __shared__ char Vs[2][4096];  // 64 rows x 64B,  slot-swizzled

  const int q0 = qt * 64 + wave * 16;
  const int kend = q0 + 16;
  const int qrow = q0 + fr;

  const bf16x8 qf0 = *(const bf16x8*)(qp + (size_t)(q0 + fr) * DHEAD + g8);
  const bf16x8 qf1 = *(const bf16x8*)(qp + (size_t)(q0 + fr) * DHEAD + 32 + g8);

  const int krow_l = lane >> 3;
  const int kslot_l = (lane & 7) ^ krow_l;
  const int vrow_l = lane >> 2;
  const int vslot_l = (lane & 3) ^ ((lane >> 3) & 3);

  const int kswz = (fr & 7) << 4;
  const int koffA = fr * 128 + ((u * 16) ^ kswz);
  const int koffB = fr * 128 + (((4 + u) * 16) ^ kswz);
  const int vswz = ((fr >> 1) & 3) << 4;

  const f32x4 fzero = {0.f, 0.f, 0.f, 0.f};
  f32x4 acc[4];
  float lpart = 0.f;
#pragma unroll
  for (int nf = 0; nf < 4; nf++) acc[nf] = fzero;

  gload_lds16(kp + (size_t)(ks0 * 32 + wave * 8 + krow_l) * DHEAD + kslot_l * 8,
              &Ks[0][wave * 1024]);
  gload_lds16(vp + (size_t)(wave * 16 + vrow_l) * T_SEQ + ks0 * 32 + vslot_l * 8,
              &Vs[0][wave * 1024]);
  __syncthreads();

  for (int ts = 0; ts < nb; ++ts) {
    const int kt = (ks0 + ts) * 32;
    const int buf = ts & 1;
    if (ts + 1 < nb) {
      const int kn = kt + 32;
      gload_lds16(kp + (size_t)(kn + wave * 8 + krow_l) * DHEAD + kslot_l * 8,
                  &Ks[buf ^ 1][wave * 1024]);
      gload_lds16(vp + (size_t)(wave * 16 + vrow_l) * T_SEQ + kn + vslot_l * 8,
                  &Vs[buf ^ 1][wave * 1024]);
    }
    if (kt < kend) {
      const char* KB = Ks[buf];
      const char* VB = Vs[buf];
      const bf16x8 kf0a = *(const bf16x8*)(KB + koffA);
      const bf16x8 kf0b = *(const bf16x8*)(KB + koffB);
      const bf16x8 kf1a = *(const bf16x8*)(KB + 2048 + koffA);
      const bf16x8 kf1b = *(const bf16x8*)(KB + 2048 + koffB);
      bf16x8 vf[4];
#pragma unroll
      for (int nf = 0; nf < 4; nf++)
        vf[nf] = *(const bf16x8*)(VB + (nf * 16 + fr) * 64 + ((u * 16) ^ vswz));

      f32x4 s0 = mfma16(kf0a, qf0, fzero);
      s0 = mfma16(kf0b, qf1, s0);
      f32x4 s1 = mfma16(kf1a, qf0, fzero);
      s1 = mfma16(kf1b, qf1, s1);

      float x0[4], x1[4];
      if (kt + 31 < q0) {
#pragma unroll
        for (int r = 0; r < 4; r++) {
          x0[r] = __expf(s0[r] * 0.125f);
          x1[r] = __expf(s1[r] * 0.125f);
          lpart += x0[r] + x1[r];
        }
      } else {
#pragma unroll
        for (int r = 0; r < 4; r++) {
          const int k0 = kt + r4 + r;
          const int k1 = k0 + 16;
          x0[r] = (k0 <= qrow) ? __expf(s0[r] * 0.125f) : 0.f;
          x1[r] = (k1 <= qrow) ? __expf(s1[r] * 0.125f) : 0.f;
          lpart += x0[r] + x1[r];
        }
      }

      // truncation-pack P^T values (bf16 pairs along k)
      const int A01 = tpack(x0[0], x0[1]);
      const int A23 = tpack(x0[2], x0[3]);
      const int B01 = tpack(x1[0], x1[1]);
      const int B23 = tpack(x1[2], x1[3]);

      const int t0a = __shfl(A01, src1), t0b = __shfl(B01, src1);
      const int t1a = __shfl(A23, src1), t1b = __shfl(B23, src1);
      const int t2a = __shfl(A01, src2), t2b = __shfl(B01, src2);
      const int t3a = __shfl(A23, src2), t3b = __shfl(B23, src2);
      i32x4 pw;
      pw[0] = hB ? t0b : t0a;
      pw[1] = hB ? t1b : t1a;
      pw[2] = hB ? t2b : t2a;
      pw[3] = hB ? t3b : t3a;
      const bf16x8 pb = __builtin_bit_cast(bf16x8, pw);

#pragma unroll
      for (int nf = 0; nf < 4; nf++) acc[nf] = mfma16(vf[nf], pb, acc[nf]);
    }
    __syncthreads();
  }

  lpart += __shfl_xor(lpart, 16);
  lpart += __shfl_xor(lpart, 32);

  if (!heavy) {
    const float inv = 1.f / lpart;
    const int t = q0 + fr;
    unsigned short* yb =
        (unsigned short*)(y + (((size_t)(b * T_SEQ + t)) * NHEAD + h) * DHEAD);
#pragma unroll
    for (int nf = 0; nf < 4; nf++) {
      ushort4 ov;
      ov.x = f2bu(acc[nf][0] * inv);
      ov.y = f2bu(acc[nf][1] * inv);
      ov.z = f2bu(acc[nf][2] * inv);
      ov.w = f2bu(acc[nf][3] * inv);
      *(ushort4*)(yb + nf * 16 + r4) = ov;
    }
  } else {
    const int big = qt >= 16;
    unsigned short* pob = big ? pO : (pO + 4194304);
    float* plb = big ? pL : (pL + 65536);
    const int rstride = big ? 1024 : 512;
    const int rbase = big ? 1024 : 512;
    const int tl = q0 - rbase + fr;
    unsigned short* po = pob + ((size_t)(hs * 32 + bh) * rstride + tl) * 64;
#pragma unroll
    for (int nf = 0; nf < 4; nf++) {
      ushort4 ov;
      ov.x = f2bu(acc[nf][0]);
      ov.y = f2bu(acc[nf][1]);
      ov.z = f2bu(acc[nf][2]);
      ov.w = f2bu(acc[nf][3]);
      *(ushort4*)(po + nf * 16 + r4) = ov;
    }
    if (lane < 16)
      plb[(size_t)(hs * 32 + bh) * rstride + (q0 - rbase) + lane] = lpart;
  }
}

// ------- combine partials: blocks 0..2047 rows 1024..2047; 2048+ rows 512..1023
__global__ __launch_bounds__(256) void comb_k(const unsigned short* __restrict__ pO,
                                              const float* __restrict__ pL,
                                              bf16* __restrict__ y) {
  if (blockIdx.x < 2048) {
    const int idx = blockIdx.x * 256 + threadIdx.x;
    const int row = idx >> 4;                        // bh*1024 + tl
    const int d0 = (idx & 15) * 4;
    const int bh = row >> 10, tl = row & 1023;
    const int b = bh >> 4, h = bh & 15;
    const int t = 1024 + tl;
    const float inv = 1.f / (pL[row] + pL[32768 + row]);
    const ushort4 a = *(const ushort4*)(pO + (size_t)row * DHEAD + d0);
    const ushort4 c = *(const ushort4*)(pO + (size_t)(32768 + row) * DHEAD + d0);
    ushort4 ov;
    ov.x = f2bu((b2f(a.x) + b2f(c.x)) * inv);
    ov.y = f2bu((b2f(a.y) + b2f(c.y)) * inv);
    ov.z = f2bu((b2f(a.z) + b2f(c.z)) * inv);
    ov.w = f2bu((b2f(a.w) + b2f(c.w)) * inv);
    *(ushort4*)((unsigned short*)y + (((size_t)(b * T_SEQ + t)) * NHEAD + h) * DHEAD + d0) = ov;
  } else {
    const int idx = (blockIdx.x - 2048) * 256 + threadIdx.x;
    const int row = idx >> 4;                        // bh*512 + tl (0..16383)
    const int d0 = (idx & 15) * 4;
    const int bh = row >> 9, tl = row & 511;
    const int b = bh >> 4, h = bh & 15;
    const int t = 512 + tl;
    const unsigned short* pOm = pO + 4194304;
    const float* pLm = pL + 65536;
    const float inv = 1.f / (pLm[row] + pLm[16384 + row]);
    const ushort4 a = *(const ushort4*)(pOm + (size_t)row * DHEAD + d0);
    const ushort4 c = *(const ushort4*)(pOm + (size_t)(16384 + row) * DHEAD + d0);
    ushort4 ov;
    ov.x = f2bu((b2f(a.x) + b2f(c.x)) * inv);
    ov.y = f2bu((b2f(a.y) + b2f(c.y)) * inv);
    ov.z = f2bu((b2f(a.z) + b2f(c.z)) * inv);
    ov.w = f2bu((b2f(a.w) + b2f(c.w)) * inv);
    *(ushort4*)((unsigned short*)y + (((size_t)(b * T_SEQ + t)) * NHEAD + h) * DHEAD + d0) = ov;
  }
}

// ---------------- launch ----------------
extern "C" void kernel_launch(void* const* d_in, const int* in_sizes, int n_in,
                              void* d_out, int out_size, void* d_ws, size_t ws_size,
                              hipStream_t stream) {
  const float* x     = (const float*)d_in[0];
  const float* ln1w  = (const float*)d_in[1];
  const float* ln2w  = (const float*)d_in[2];
  const float* qkvw  = (const float*)d_in[3];
  const float* ow    = (const float*)d_in[4];
  const float* gatew = (const float*)d_in[5];
  const float* upw   = (const float*)d_in[6];
  const float* downw = (const float*)d_in[7];

  uint8_t* ws = (uint8_t*)d_ws;
  bf16* WQKV = (bf16*)(ws + 0);          // 6291456
  bf16* WO   = (bf16*)(ws + 6291456);    // 2097152
  bf16* WGU  = (bf16*)(ws + 8388608);    // 8388608  (4096 x 1024, rows interleaved g/u)
  bf16* WD   = (bf16*)(ws + 16777216);   // 4194304
  bf16* H    = (bf16*)(ws + 20971520);   // 8388608
  bf16* Q    = (bf16*)(ws + 29360128);   // 8388608
  bf16* Kb   = (bf16*)(ws + 37748736);   // 8388608
  bf16* VT   = (bf16*)(ws + 46137344);   // 8388608  (B,H,64,T)
  bf16* Y    = (bf16*)(ws + 54525952);   // 8388608
  float* X2  = (float*)(ws + 62914560);  // 16777216 -> end 79691776
  bf16* G = (bf16*)(ws + 29360128);      // FFN alias: silu(g)*u (4096 x 2048)
  unsigned short* pO = (unsigned short*)(ws + 62914560);  // 8MB heavy + 4MB medium (X2)
  float* pL = (float*)(ws + 20971520);                    // 256KB + 128KB lsums (H)

  // fused: weights->bf16 (blocks 0..10239) + rms1 (blocks 10240..14335)
  prep_k<<<14336, 256, 0, stream>>>(qkvw, ow, gatew, upw, downw, (bf16*)ws,
                                    x, ln1w, H);

  // attn path
  gemm_bt<1024, 1><<<dim3(24, 32), 256, 0, stream>>>(H, WQKV, 3072, Q, Kb, VT, nullptr);
  attn_k<<<1792, 256, 0, stream>>>(Q, Kb, VT, Y, pO, pL);
  comb_k<<<3072, 256, 0, stream>>>(pO, pL, Y);
  gemm_bt<1024, 2><<<dim3(8, 32), 256, 0, stream>>>(Y, WO, 1024, X2, nullptr, nullptr, x);

  // ffn path: fused gate+up GEMM with silu epilogue -> G, then down GEMM
  rms_k<<<MROWS, 256, 0, stream>>>(X2, ln2w, H);
  gemm_bt<1024, 4><<<dim3(32, 32), 256, 0, stream>>>(H, WGU, 4096, G, nullptr, nullptr, nullptr);
  gemm_bt<2048, 2><<<dim3(8, 32), 256, 0, stream>>>(G, WD, 1024, (float*)d_out, nullptr, nullptr, X2);
}

// Round 22
// 222.096 us; speedup vs baseline: 1.0166x; 1.0166x over previous
//
#include <hip/hip_runtime.h>
#include <hip/hip_bf16.h>
#include <cstdint>

typedef __hip_bfloat16 bf16;
typedef __attribute__((ext_vector_type(8))) short bf16x8;
typedef __attribute__((ext_vector_type(4))) float f32x4;
typedef __attribute__((ext_vector_type(4))) int i32x4;

#define T_SEQ 2048
#define DMODEL 1024
#define NHEAD 16
#define DHEAD 64
#define MROWS 4096

typedef const __attribute__((address_space(1))) void* gas_ptr;
typedef __attribute__((address_space(3))) void* las_ptr;

static __device__ __forceinline__ f32x4 mfma16(bf16x8 a, bf16x8 b, f32x4 c) {
  return __builtin_amdgcn_mfma_f32_16x16x32_bf16(a, b, c, 0, 0, 0);
}
static __device__ __forceinline__ void gload_lds16(const void* g, void* l) {
  __builtin_amdgcn_global_load_lds((gas_ptr)g, (las_ptr)l, 16, 0, 0);
}
static __device__ __forceinline__ float b2f(unsigned short u) {
  union { unsigned int i; float f; } x; x.i = ((unsigned int)u) << 16; return x.f;
}
static __device__ __forceinline__ unsigned short f2bu(float f) {
  __hip_bfloat16 h = __float2bfloat16(f);
  unsigned short u; __builtin_memcpy(&u, &h, 2); return u;
}
// truncation pack: low16 = bf16_trunc(a), high16 = bf16_trunc(b); a,b >= 0
static __device__ __forceinline__ int tpack(float a, float b) {
  const unsigned ua = __builtin_bit_cast(unsigned, a);
  const unsigned ub = __builtin_bit_cast(unsigned, b);
  return (int)((ua >> 16) | (ub & 0xFFFF0000u));
}

// ------- prep: weights fp32->bf16 (blocks 0..10239) + rms1 (blocks 10240+) ---
// gate/up rows are INTERLEAVED into WGU: row 2i = gate_i, row 2i+1 = up_i.
__global__ __launch_bounds__(256) void prep_k(const float* __restrict__ a,
                                              const float* __restrict__ b,
                                              const float* __restrict__ c,
                                              const float* __restrict__ d,
                                              const float* __restrict__ e,
                                              bf16* __restrict__ out,
                                              const float* __restrict__ x,
                                              const float* __restrict__ ln1w,
                                              bf16* __restrict__ H) {
  if (blockIdx.x < 10240) {
    const int idx = (blockIdx.x * 256 + threadIdx.x) * 4;
    const float* src;
    int off, dst;
    if (idx < 3145728) {                     // qkv
      src = a; off = idx; dst = idx;
    } else if (idx < 4194304) {              // o
      src = b; off = idx - 3145728; dst = idx;
    } else if (idx < 6291456) {              // gate -> WGU even rows
      src = c; off = idx - 4194304;
      dst = 4194304 + ((off >> 10) << 11) + (off & 1023);
    } else if (idx < 8388608) {              // up -> WGU odd rows
      src = d; off = idx - 6291456;
      dst = 4194304 + ((off >> 10) << 11) + 1024 + (off & 1023);
    } else {                                 // down
      src = e; off = idx - 8388608; dst = idx;
    }
    const float4 v = *(const float4*)(src + off);
    ushort4 ov;
    ov.x = f2bu(v.x); ov.y = f2bu(v.y); ov.z = f2bu(v.z); ov.w = f2bu(v.w);
    *(ushort4*)((unsigned short*)out + dst) = ov;
  } else {
    const int row = blockIdx.x - 10240;
    const int tid = threadIdx.x;
    const float4 v = ((const float4*)(x + (size_t)row * DMODEL))[tid];
    float ss = v.x * v.x + v.y * v.y + v.z * v.z + v.w * v.w;
#pragma unroll
    for (int off = 32; off; off >>= 1) ss += __shfl_xor(ss, off);
    __shared__ float red[4];
    if ((tid & 63) == 0) red[tid >> 6] = ss;
    __syncthreads();
    const float tot = red[0] + red[1] + red[2] + red[3];
    const float rinv = rsqrtf(tot * (1.f / DMODEL) + 1e-6f);
    const float4 wv = ((const float4*)ln1w)[tid];
    bf16* o = H + (size_t)row * DMODEL + tid * 4;
    o[0] = __float2bfloat16(v.x * rinv * wv.x);
    o[1] = __float2bfloat16(v.y * rinv * wv.y);
    o[2] = __float2bfloat16(v.z * rinv * wv.z);
    o[3] = __float2bfloat16(v.w * rinv * wv.w);
  }
}

// ---------------- RMSNorm: fp32 in -> bf16 out (used for rms2) ----------------
__global__ __launch_bounds__(256) void rms_k(const float* __restrict__ x,
                                             const float* __restrict__ w,
                                             bf16* __restrict__ out) {
  const int row = blockIdx.x;
  const int tid = threadIdx.x;
  const float4 v = ((const float4*)(x + (size_t)row * DMODEL))[tid];
  float ss = v.x * v.x + v.y * v.y + v.z * v.z + v.w * v.w;
#pragma unroll
  for (int off = 32; off; off >>= 1) ss += __shfl_xor(ss, off);
  __shared__ float red[4];
  if ((tid & 63) == 0) red[tid >> 6] = ss;
  __syncthreads();
  const float tot = red[0] + red[1] + red[2] + red[3];
  const float rinv = rsqrtf(tot * (1.f / DMODEL) + 1e-6f);
  const float4 wv = ((const float4*)w)[tid];
  bf16* o = out + (size_t)row * DMODEL + tid * 4;
  o[0] = __float2bfloat16(v.x * rinv * wv.x);
  o[1] = __float2bfloat16(v.y * rinv * wv.y);
  o[2] = __float2bfloat16(v.z * rinv * wv.z);
  o[3] = __float2bfloat16(v.w * rinv * wv.w);
}

// ---------------- GEMM: C = A(M,K) x Bw(N,K)^T, bf16 in, fp32 accum ----------------
// r14/r15-verified: 2-barrier structure, BK=64, both-sides 16B-slot XOR swizzle
// (bank conflicts = 0 measured). V^T stores PACKED (8B).
// EPI: 1 = qkv scatter: Q,K as (B,H,T,64) to o0/o1; V TRANSPOSED (B,H,64,T) to o2
//      2 = fp32 store o0 = res + C (ld=N)
//      4 = fused gate/up (B = row-interleaved WGU): even col=gate, odd col=up;
//          even lanes compute silu(g)*u -> bf16 store to o0 (ld = N/2)
template <int K, int EPI>
__global__ __launch_bounds__(256) void gemm_bt(const bf16* __restrict__ A,
                                               const bf16* __restrict__ Bw, int N,
                                               void* __restrict__ o0, void* __restrict__ o1,
                                               void* __restrict__ o2,
                                               const float* __restrict__ res) {
  __shared__ bf16 As[128 * 64];
  __shared__ bf16 Bs[128 * 64];
  const int bn0 = blockIdx.x * 128;
  const int bm0 = blockIdx.y * 128;
  const int tid = threadIdx.x;
  const int wave = tid >> 6, lane = tid & 63;
  const int wr = wave >> 1, wc = wave & 1;
  const int fr = lane & 15, u = lane >> 4, r4 = u * 4;
  const int srow = lane >> 3;              // 0..7 within 8-row chunk
  const int sslot = (lane & 7) ^ srow;     // pre-swizzled source 16B slot
  const int fsw = fr & 7;

  const f32x4 fzero = {0.f, 0.f, 0.f, 0.f};
  f32x4 acc[4][4];
#pragma unroll
  for (int i = 0; i < 4; i++)
#pragma unroll
    for (int j = 0; j < 4; j++) acc[i][j] = fzero;

  const bf16* gA = A + (size_t)(bm0 + wave * 32 + srow) * K + sslot * 8;
  const bf16* gB = Bw + (size_t)(bn0 + wave * 32 + srow) * K + sslot * 8;

  for (int k0 = 0; k0 < K; k0 += 64) {
#pragma unroll
    for (int j = 0; j < 4; j++)
      gload_lds16(gA + (size_t)(j * 8) * K + k0, &As[(wave * 32 + j * 8) * 64]);
#pragma unroll
    for (int j = 0; j < 4; j++)
      gload_lds16(gB + (size_t)(j * 8) * K + k0, &Bs[(wave * 32 + j * 8) * 64]);
    __syncthreads();
#pragma unroll
    for (int kh = 0; kh < 2; kh++) {
      const int slot8 = ((kh * 4 + u) ^ fsw) * 8;
      bf16x8 af[4], bfr[4];
#pragma unroll
      for (int mr = 0; mr < 4; mr++)
        af[mr] = *(const bf16x8*)&As[(wr * 64 + mr * 16 + fr) * 64 + slot8];
#pragma unroll
      for (int nr = 0; nr < 4; nr++)
        bfr[nr] = *(const bf16x8*)&Bs[(wc * 64 + nr * 16 + fr) * 64 + slot8];
#pragma unroll
      for (int mr = 0; mr < 4; mr++)
#pragma unroll
        for (int nr = 0; nr < 4; nr++)
          acc[mr][nr] = mfma16(af[mr], bfr[nr], acc[mr][nr]);
    }
    __syncthreads();
  }

#pragma unroll
  for (int mr = 0; mr < 4; mr++) {
#pragma unroll
    for (int nr = 0; nr < 4; nr++) {
      if (EPI == 1) {
        const int col = bn0 + wc * 64 + nr * 16 + fr;
        const int sel = col >> 10;
        const int n = col & 1023;
        const int h = n >> 6, d = n & 63;
        const int row0 = bm0 + wr * 64 + mr * 16 + r4;  // 4 consecutive rows
        const int b = row0 >> 11, t0 = row0 & 2047;     // never crosses 2048
        if (sel == 2) {
          // V transposed (B,H,64,T): 4 consecutive t -> one 8B store
          ushort4 ov;
          ov.x = f2bu(acc[mr][nr][0]);
          ov.y = f2bu(acc[mr][nr][1]);
          ov.z = f2bu(acc[mr][nr][2]);
          ov.w = f2bu(acc[mr][nr][3]);
          *(ushort4*)((unsigned short*)o2 +
                      (((size_t)(b * NHEAD + h)) * DHEAD + d) * T_SEQ + t0) = ov;
        } else {
          bf16* dst = (sel == 0) ? (bf16*)o0 : (bf16*)o1;
#pragma unroll
          for (int r = 0; r < 4; r++)
            dst[(((size_t)(b * NHEAD + h)) * T_SEQ + t0 + r) * DHEAD + d] =
                __float2bfloat16(acc[mr][nr][r]);
        }
      } else {
#pragma unroll
        for (int r = 0; r < 4; r++) {
          const int row = bm0 + wr * 64 + mr * 16 + r4 + r;
          const int col = bn0 + wc * 64 + nr * 16 + fr;
          const float vsum = acc[mr][nr][r];
          if (EPI == 2) {
            ((float*)o0)[(size_t)row * N + col] = res[(size_t)row * N + col] + vsum;
          } else {  // EPI == 4: fused gate/up + silu
            const float other = __shfl_xor(vsum, 1);
            if ((fr & 1) == 0) {
              const float g = vsum, uu = other;
              const float s = g / (1.f + __expf(-g));
              ((bf16*)o0)[(size_t)row * (N >> 1) + (col >> 1)] =
                  __float2bfloat16(s * uu);
            }
          }
        }
      }
    }
  }
}

// ---------------- causal flash attention, shared LDS staging + heavy key-split
// r17/r20-verified best configuration EXACTLY: 32-key tiles, __expf(s*0.125),
// truncation-packed P, no setprio (barrier-lockstep regime), heavy key-split
// at qt>=16 only (r21's qt>=8 split raised occupancy but cost more in partial
// traffic than it saved).
__global__ __launch_bounds__(256) void attn_k(const bf16* __restrict__ qb,
                                              const bf16* __restrict__ kb,
                                              const bf16* __restrict__ vt,
                                              bf16* __restrict__ y,
                                              unsigned short* __restrict__ pO,
                                              float* __restrict__ pL) {
  const int wave = threadIdx.x >> 6, lane = threadIdx.x & 63;
  const int bid = blockIdx.x;
  int bh, qt, ks0, nb, heavy, hs;
  if (bid < 1024) {
    const int c = bid & 7, r = bid >> 3;
    bh = c * 4 + (r & 3);
    const int idx = r >> 2;
    qt = 31 - (idx >> 1);
    hs = idx & 1;
    heavy = 1;
    nb = qt + 1;
    ks0 = hs * nb;
  } else {
    const int bd = bid - 1024;
    const int c = bd & 7, r = bd >> 3;
    bh = c * 4 + (r & 3);
    qt = 15 - (r >> 2);
    hs = 0;
    heavy = 0;
    nb = 2 * qt + 2;
    ks0 = 0;
  }
  const int b = bh >> 4, h = bh & 15;
  const int fr = lane & 15, g8 = (lane >> 4) * 8, r4 = (lane >> 4) * 4;
  const int u = lane >> 4;
  const int src1 = fr + ((u & 1) << 5);
  const int src2 = src1 + 16;
  const bool hB = u >= 2;

  const bf16* qp = qb + (size_t)bh * T_SEQ * DHEAD;
  const bf16* kp = kb + (size_t)bh * T_SEQ * DHEAD;
  const bf16* vp = vt + (size_t)bh * DHEAD * T_SEQ;

  __shared__ char Ks[2][4096];  // 32 rows x 128B, slot-swizzled
  __shared__ char Vs[2][4096];  // 64 rows x 64B,  slot-swizzled

  const int q0 = qt * 64 + wave * 16;
  const int kend = q0 + 16;
  const int qrow = q0 + fr;

  const bf16x8 qf0 = *(const bf16x8*)(qp + (size_t)(q0 + fr) * DHEAD + g8);
  const bf16x8 qf1 = *(const bf16x8*)(qp + (size_t)(q0 + fr) * DHEAD + 32 + g8);

  const int krow_l = lane >> 3;
  const int kslot_l = (lane & 7) ^ krow_l;
  const int vrow_l = lane >> 2;
  const int vslot_l = (lane & 3) ^ ((lane >> 3) & 3);

  const int kswz = (fr & 7) << 4;
  const int koffA = fr * 128 + ((u * 16) ^ kswz);
  const int koffB = fr * 128 + (((4 + u) * 16) ^ kswz);
  const int vswz = ((fr >> 1) & 3) << 4;

  const f32x4 fzero = {0.f, 0.f, 0.f, 0.f};
  f32x4 acc[4];
  float lpart = 0.f;
#pragma unroll
  for (int nf = 0; nf < 4; nf++) acc[nf] = fzero;

  gload_lds16(kp + (size_t)(ks0 * 32 + wave * 8 + krow_l) * DHEAD + kslot_l * 8,
              &Ks[0][wave * 1024]);
  gload_lds16(vp + (size_t)(wave * 16 + vrow_l) * T_SEQ + ks0 * 32 + vslot_l * 8,
              &Vs[0][wave * 1024]);
  __syncthreads();

  for (int ts = 0; ts < nb; ++ts) {
    const int kt = (ks0 + ts) * 32;
    const int buf = ts & 1;
    if (ts + 1 < nb) {
      const int kn = kt + 32;
      gload_lds16(kp + (size_t)(kn + wave * 8 + krow_l) * DHEAD + kslot_l * 8,
                  &Ks[buf ^ 1][wave * 1024]);
      gload_lds16(vp + (size_t)(wave * 16 + vrow_l) * T_SEQ + kn + vslot_l * 8,
                  &Vs[buf ^ 1][wave * 1024]);
    }
    if (kt < kend) {
      const char* KB = Ks[buf];
      const char* VB = Vs[buf];
      const bf16x8 kf0a = *(const bf16x8*)(KB + koffA);
      const bf16x8 kf0b = *(const bf16x8*)(KB + koffB);
      const bf16x8 kf1a = *(const bf16x8*)(KB + 2048 + koffA);
      const bf16x8 kf1b = *(const bf16x8*)(KB + 2048 + koffB);
      bf16x8 vf[4];
#pragma unroll
      for (int nf = 0; nf < 4; nf++)
        vf[nf] = *(const bf16x8*)(VB + (nf * 16 + fr) * 64 + ((u * 16) ^ vswz));

      f32x4 s0 = mfma16(kf0a, qf0, fzero);
      s0 = mfma16(kf0b, qf1, s0);
      f32x4 s1 = mfma16(kf1a, qf0, fzero);
      s1 = mfma16(kf1b, qf1, s1);

      float x0[4], x1[4];
      if (kt + 31 < q0) {
#pragma unroll
        for (int r = 0; r < 4; r++) {
          x0[r] = __expf(s0[r] * 0.125f);
          x1[r] = __expf(s1[r] * 0.125f);
          lpart += x0[r] + x1[r];
        }
      } else {
#pragma unroll
        for (int r = 0; r < 4; r++) {
          const int k0 = kt + r4 + r;
          const int k1 = k0 + 16;
          x0[r] = (k0 <= qrow) ? __expf(s0[r] * 0.125f) : 0.f;
          x1[r] = (k1 <= qrow) ? __expf(s1[r] * 0.125f) : 0.f;
          lpart += x0[r] + x1[r];
        }
      }

      // truncation-pack P^T values (bf16 pairs along k)
      const int A01 = tpack(x0[0], x0[1]);
      const int A23 = tpack(x0[2], x0[3]);
      const int B01 = tpack(x1[0], x1[1]);
      const int B23 = tpack(x1[2], x1[3]);

      const int t0a = __shfl(A01, src1), t0b = __shfl(B01, src1);
      const int t1a = __shfl(A23, src1), t1b = __shfl(B23, src1);
      const int t2a = __shfl(A01, src2), t2b = __shfl(B01, src2);
      const int t3a = __shfl(A23, src2), t3b = __shfl(B23, src2);
      i32x4 pw;
      pw[0] = hB ? t0b : t0a;
      pw[1] = hB ? t1b : t1a;
      pw[2] = hB ? t2b : t2a;
      pw[3] = hB ? t3b : t3a;
      const bf16x8 pb = __builtin_bit_cast(bf16x8, pw);

#pragma unroll
      for (int nf = 0; nf < 4; nf++) acc[nf] = mfma16(vf[nf], pb, acc[nf]);
    }
    __syncthreads();
  }

  lpart += __shfl_xor(lpart, 16);
  lpart += __shfl_xor(lpart, 32);

  if (!heavy) {
    const float inv = 1.f / lpart;
    const int t = q0 + fr;
    unsigned short* yb =
        (unsigned short*)(y + (((size_t)(b * T_SEQ + t)) * NHEAD + h) * DHEAD);
#pragma unroll
    for (int nf = 0; nf < 4; nf++) {
      ushort4 ov;
      ov.x = f2bu(acc[nf][0] * inv);
      ov.y = f2bu(acc[nf][1] * inv);
      ov.z = f2bu(acc[nf][2] * inv);
      ov.w = f2bu(acc[nf][3] * inv);
      *(ushort4*)(yb + nf * 16 + r4) = ov;
    }
  } else {
    const int tl = q0 - 1024 + fr;
    unsigned short* po = pO + ((size_t)(hs * 32 + bh) * 1024 + tl) * DHEAD;
#pragma unroll
    for (int nf = 0; nf < 4; nf++) {
      ushort4 ov;
      ov.x = f2bu(acc[nf][0]);
      ov.y = f2bu(acc[nf][1]);
      ov.z = f2bu(acc[nf][2]);
      ov.w = f2bu(acc[nf][3]);
      *(ushort4*)(po + nf * 16 + r4) = ov;
    }
    if (lane < 16) pL[(size_t)(hs * 32 + bh) * 1024 + (q0 - 1024) + lane] = lpart;
  }
}

// ---------------- combine heavy partials -> Y rows 1024..2047 ----------------
__global__ __launch_bounds__(256) void comb_k(const unsigned short* __restrict__ pO,
                                              const float* __restrict__ pL,
                                              bf16* __restrict__ y) {
  const int idx = blockIdx.x * 256 + threadIdx.x;
  const int row = idx >> 4;
  const int d0 = (idx & 15) * 4;
  const int bh = row >> 10, tl = row & 1023;
  const int b = bh >> 4, h = bh & 15;
  const int t = 1024 + tl;
  const float inv = 1.f / (pL[row] + pL[32768 + row]);
  const ushort4 a = *(const ushort4*)(pO + (size_t)row * DHEAD + d0);
  const ushort4 c = *(const ushort4*)(pO + (size_t)(32768 + row) * DHEAD + d0);
  ushort4 ov;
  ov.x = f2bu((b2f(a.x) + b2f(c.x)) * inv);
  ov.y = f2bu((b2f(a.y) + b2f(c.y)) * inv);
  ov.z = f2bu((b2f(a.z) + b2f(c.z)) * inv);
  ov.w = f2bu((b2f(a.w) + b2f(c.w)) * inv);
  *(ushort4*)((unsigned short*)y + (((size_t)(b * T_SEQ + t)) * NHEAD + h) * DHEAD + d0) = ov;
}

// ---------------- launch ----------------
extern "C" void kernel_launch(void* const* d_in, const int* in_sizes, int n_in,
                              void* d_out, int out_size, void* d_ws, size_t ws_size,
                              hipStream_t stream) {
  const float* x     = (const float*)d_in[0];
  const float* ln1w  = (const float*)d_in[1];
  const float* ln2w  = (const float*)d_in[2];
  const float* qkvw  = (const float*)d_in[3];
  const float* ow    = (const float*)d_in[4];
  const float* gatew = (const float*)d_in[5];
  const float* upw   = (const float*)d_in[6];
  const float* downw = (const float*)d_in[7];

  uint8_t* ws = (uint8_t*)d_ws;
  bf16* WQKV = (bf16*)(ws + 0);          // 6291456
  bf16* WO   = (bf16*)(ws + 6291456);    // 2097152
  bf16* WGU  = (bf16*)(ws + 8388608);    // 8388608  (4096 x 1024, rows interleaved g/u)
  bf16* WD   = (bf16*)(ws + 16777216);   // 4194304
  bf16* H    = (bf16*)(ws + 20971520);   // 8388608
  bf16* Q    = (bf16*)(ws + 29360128);   // 8388608
  bf16* Kb   = (bf16*)(ws + 37748736);   // 8388608
  bf16* VT   = (bf16*)(ws + 46137344);   // 8388608  (B,H,64,T)
  bf16* Y    = (bf16*)(ws + 54525952);   // 8388608
  float* X2  = (float*)(ws + 62914560);  // 16777216 -> end 79691776
  bf16* G = (bf16*)(ws + 29360128);      // FFN alias: silu(g)*u (4096 x 2048)
  unsigned short* pO = (unsigned short*)(ws + 62914560);  // attn partials (X2 region)
  float* pL = (float*)(ws + 20971520);                    // attn lsums (H region)

  // fused: weights->bf16 (blocks 0..10239) + rms1 (blocks 10240..14335)
  prep_k<<<14336, 256, 0, stream>>>(qkvw, ow, gatew, upw, downw, (bf16*)ws,
                                    x, ln1w, H);

  // attn path
  gemm_bt<1024, 1><<<dim3(24, 32), 256, 0, stream>>>(H, WQKV, 3072, Q, Kb, VT, nullptr);
  attn_k<<<1536, 256, 0, stream>>>(Q, Kb, VT, Y, pO, pL);
  comb_k<<<2048, 256, 0, stream>>>(pO, pL, Y);
  gemm_bt<1024, 2><<<dim3(8, 32), 256, 0, stream>>>(Y, WO, 1024, X2, nullptr, nullptr, x);

  // ffn path: fused gate+up GEMM with silu epilogue -> G, then down GEMM
  rms_k<<<MROWS, 256, 0, stream>>>(X2, ln2w, H);
  gemm_bt<1024, 4><<<dim3(32, 32), 256, 0, stream>>>(H, WGU, 4096, G, nullptr, nullptr, nullptr);
  gemm_bt<2048, 2><<<dim3(8, 32), 256, 0, stream>>>(G, WD, 1024, (float*)d_out, nullptr, nullptr, X2);
}